// Round 1
// baseline (613.328 us; speedup 1.0000x reference)
//
#include <hip/hip_runtime.h>
#include <hip/hip_bf16.h>

#define N_SEQ 2048
#define DSTR 1024
#define NH 32          // B*HEADS
#define QKVN 3072      // HEADS*D_HEAD
#define MROWS 4096     // N*B

typedef float f32x4 __attribute__((ext_vector_type(4)));
typedef short bf16x8 __attribute__((ext_vector_type(8)));
typedef unsigned short u16t;

__device__ __forceinline__ u16t f2bf(float f) {
  union { float f; unsigned u; } x; x.f = f;
  return (u16t)((x.u + 0x7fff + ((x.u >> 16) & 1)) >> 16);
}
__device__ __forceinline__ float bf2f(u16t u) {
  union { unsigned u; float f; } x; x.u = ((unsigned)u) << 16; return x.f;
}

#define MFMA16(a, b, c) __builtin_amdgcn_mfma_f32_16x16x32_bf16(a, b, c, 0, 0, 0)

// ---------------- transpose + bf16 split: in fp32 [K][Nc] -> hi/lo bf16 [Nc][K]
__global__ void transpose_split_kernel(const float* __restrict__ in,
                                       u16t* __restrict__ hi, u16t* __restrict__ lo,
                                       int K, int Nc) {
  __shared__ float tile[32][33];
  const int n0 = blockIdx.x * 32, k0 = blockIdx.y * 32;
  const int tx = threadIdx.x, ty = threadIdx.y;
  #pragma unroll
  for (int j = 0; j < 32; j += 8)
    tile[ty + j][tx] = in[(size_t)(k0 + ty + j) * Nc + n0 + tx];
  __syncthreads();
  #pragma unroll
  for (int j = 0; j < 32; j += 8) {
    float v = tile[tx][ty + j];
    size_t o = (size_t)(n0 + ty + j) * K + k0 + tx;
    u16t h = f2bf(v);
    hi[o] = h;
    if (lo) lo[o] = f2bf(v - bf2f(h));
  }
}

// ---------------- GEMM 1: qkv = stream @ w_qkv + b_qkv, split-precision
__global__ __launch_bounds__(256) void gemm_qkv_kernel(
    const float* __restrict__ A, const u16t* __restrict__ Bhi,
    const u16t* __restrict__ Blo, const float* __restrict__ bias,
    u16t* __restrict__ Qhi, u16t* __restrict__ Qlo,
    u16t* __restrict__ Khi, u16t* __restrict__ Klo,
    u16t* __restrict__ Vt) {
  constexpr int BM = 128, BK = 32, LDT = 40;
  __shared__ u16t sAhi[BM * LDT], sAlo[BM * LDT], sBhi[BM * LDT], sBlo[BM * LDT];
  const int t = threadIdx.x;
  const int lane = t & 63, wid = t >> 6;
  const int wm = wid >> 1, wn = wid & 1;
  const int g = lane >> 4, cc = lane & 15;
  const int m0 = blockIdx.x * BM, n0 = blockIdx.y * BM;
  const int srow = t >> 1, sseg = (t & 1) * 16;

  f32x4 acc[4][4] = {};

  for (int k0 = 0; k0 < DSTR; k0 += BK) {
    __syncthreads();
    {  // stage A fp32 -> hi/lo bf16
      const float* src = A + (size_t)(m0 + srow) * DSTR + k0 + sseg;
      u16t hbuf[16], lbuf[16];
      #pragma unroll
      for (int j = 0; j < 16; j += 4) {
        float4 v = *(const float4*)(src + j);
        float vv[4] = {v.x, v.y, v.z, v.w};
        #pragma unroll
        for (int i = 0; i < 4; i++) {
          u16t hh = f2bf(vv[i]);
          hbuf[j + i] = hh;
          lbuf[j + i] = f2bf(vv[i] - bf2f(hh));
        }
      }
      *(bf16x8*)&sAhi[srow * LDT + sseg]     = *(bf16x8*)&hbuf[0];
      *(bf16x8*)&sAhi[srow * LDT + sseg + 8] = *(bf16x8*)&hbuf[8];
      *(bf16x8*)&sAlo[srow * LDT + sseg]     = *(bf16x8*)&lbuf[0];
      *(bf16x8*)&sAlo[srow * LDT + sseg + 8] = *(bf16x8*)&lbuf[8];
    }
    {  // stage B (pre-split bf16, N-major)
      const u16t* srcH = Bhi + (size_t)(n0 + srow) * DSTR + k0 + sseg;
      const u16t* srcL = Blo + (size_t)(n0 + srow) * DSTR + k0 + sseg;
      *(bf16x8*)&sBhi[srow * LDT + sseg]     = *(const bf16x8*)(srcH);
      *(bf16x8*)&sBhi[srow * LDT + sseg + 8] = *(const bf16x8*)(srcH + 8);
      *(bf16x8*)&sBlo[srow * LDT + sseg]     = *(const bf16x8*)(srcL);
      *(bf16x8*)&sBlo[srow * LDT + sseg + 8] = *(const bf16x8*)(srcL + 8);
    }
    __syncthreads();
    bf16x8 ah[4], al[4], bh[4], bl[4];
    #pragma unroll
    for (int mt = 0; mt < 4; mt++) {
      int r = wm * 64 + mt * 16 + cc;
      ah[mt] = *(const bf16x8*)&sAhi[r * LDT + g * 8];
      al[mt] = *(const bf16x8*)&sAlo[r * LDT + g * 8];
    }
    #pragma unroll
    for (int nt = 0; nt < 4; nt++) {
      int r = wn * 64 + nt * 16 + cc;
      bh[nt] = *(const bf16x8*)&sBhi[r * LDT + g * 8];
      bl[nt] = *(const bf16x8*)&sBlo[r * LDT + g * 8];
    }
    #pragma unroll
    for (int mt = 0; mt < 4; mt++)
      #pragma unroll
      for (int nt = 0; nt < 4; nt++) {
        acc[mt][nt] = MFMA16(ah[mt], bh[nt], acc[mt][nt]);
        acc[mt][nt] = MFMA16(al[mt], bh[nt], acc[mt][nt]);
        acc[mt][nt] = MFMA16(ah[mt], bl[nt], acc[mt][nt]);
      }
  }
  // epilogue: add bias, scatter into Qhi/Qlo/Khi/Klo/Vt
  #pragma unroll
  for (int mt = 0; mt < 4; mt++)
    #pragma unroll
    for (int nt = 0; nt < 4; nt++)
      #pragma unroll
      for (int r = 0; r < 4; r++) {
        int grow = m0 + wm * 64 + mt * 16 + g * 4 + r;
        int gcol = n0 + wn * 64 + nt * 16 + cc;
        float val = acc[mt][nt][r] + bias[gcol];
        int nn = grow >> 1, bb = grow & 1;
        int hl = gcol / 192, off = gcol - hl * 192;
        int hh = bb * 16 + hl;
        if (off < 64) {
          size_t o = ((size_t)hh * N_SEQ + nn) * 64 + off;
          u16t h_ = f2bf(val);
          Qhi[o] = h_;
          Qlo[o] = f2bf(val - bf2f(h_));
        } else if (off < 128) {
          size_t o = ((size_t)hh * N_SEQ + nn) * 64 + (off - 64);
          u16t h_ = f2bf(val);
          Khi[o] = h_;
          Klo[o] = f2bf(val - bf2f(h_));
        } else {
          Vt[((size_t)hh * 64 + (off - 128)) * N_SEQ + nn] = f2bf(val);
        }
      }
}

// ---------------- flash attention, split-precision QK^T
__global__ __launch_bounds__(256) void attn_kernel(
    const u16t* __restrict__ Qhi, const u16t* __restrict__ Qlo,
    const u16t* __restrict__ Khi, const u16t* __restrict__ Klo,
    const u16t* __restrict__ Vt, const float* __restrict__ mask,
    u16t* __restrict__ Vals) {
  __shared__ u16t Plds[4][16 * 56];
  const int t = threadIdx.x;
  const int lane = t & 63, wid = t >> 6;
  const int g = lane >> 4, cc = lane & 15;
  const int h = blockIdx.x >> 5;
  const int qt = blockIdx.x & 31;
  const int q0 = qt * 64 + wid * 16;

  const u16t* qh_base = Qhi + ((size_t)h * N_SEQ + q0 + cc) * 64 + g * 8;
  const u16t* ql_base = Qlo + ((size_t)h * N_SEQ + q0 + cc) * 64 + g * 8;
  bf16x8 qh0 = *(const bf16x8*)(qh_base);
  bf16x8 qh1 = *(const bf16x8*)(qh_base + 32);
  bf16x8 ql0 = *(const bf16x8*)(ql_base);
  bf16x8 ql1 = *(const bf16x8*)(ql_base + 32);

  f32x4 o[4] = {};
  float M[4], L[4];
  #pragma unroll
  for (int r = 0; r < 4; r++) { M[r] = -1e30f; L[r] = 0.0f; }

  u16t* P = Plds[wid];

  for (int m0 = 0; m0 < N_SEQ; m0 += 32) {
    f32x4 s[2] = {};
    #pragma unroll
    for (int mt = 0; mt < 2; mt++) {
      const u16t* kh = Khi + ((size_t)h * N_SEQ + m0 + mt * 16 + cc) * 64 + g * 8;
      const u16t* kl = Klo + ((size_t)h * N_SEQ + m0 + mt * 16 + cc) * 64 + g * 8;
      bf16x8 kh0 = *(const bf16x8*)(kh);
      bf16x8 kh1 = *(const bf16x8*)(kh + 32);
      bf16x8 kl0 = *(const bf16x8*)(kl);
      bf16x8 kl1 = *(const bf16x8*)(kl + 32);
      s[mt] = MFMA16(qh0, kh0, s[mt]);
      s[mt] = MFMA16(qh1, kh1, s[mt]);
      s[mt] = MFMA16(ql0, kh0, s[mt]);
      s[mt] = MFMA16(ql1, kh1, s[mt]);
      s[mt] = MFMA16(qh0, kl0, s[mt]);
      s[mt] = MFMA16(qh1, kl1, s[mt]);
    }
    #pragma unroll
    for (int r = 0; r < 4; r++) {
      const int q = q0 + g * 4 + r;
      s[0][r] += mask[(size_t)q * N_SEQ + m0 + cc];
      s[1][r] += mask[(size_t)q * N_SEQ + m0 + 16 + cc];
    }
    #pragma unroll
    for (int r = 0; r < 4; r++) {
      float mx = fmaxf(s[0][r], s[1][r]);
      mx = fmaxf(mx, __shfl_xor(mx, 1, 16));
      mx = fmaxf(mx, __shfl_xor(mx, 2, 16));
      mx = fmaxf(mx, __shfl_xor(mx, 4, 16));
      mx = fmaxf(mx, __shfl_xor(mx, 8, 16));
      float newM = fmaxf(M[r], mx);
      float alpha = __expf(M[r] - newM);
      float p0 = __expf(s[0][r] - newM);
      float p1 = __expf(s[1][r] - newM);
      s[0][r] = p0; s[1][r] = p1;
      float rs = p0 + p1;
      rs += __shfl_xor(rs, 1, 16);
      rs += __shfl_xor(rs, 2, 16);
      rs += __shfl_xor(rs, 4, 16);
      rs += __shfl_xor(rs, 8, 16);
      L[r] = L[r] * alpha + rs;
      M[r] = newM;
      o[0][r] *= alpha; o[1][r] *= alpha; o[2][r] *= alpha; o[3][r] *= alpha;
    }
    #pragma unroll
    for (int r = 0; r < 4; r++) {
      P[(g * 4 + r) * 56 + cc]      = f2bf(s[0][r]);
      P[(g * 4 + r) * 56 + 16 + cc] = f2bf(s[1][r]);
    }
    bf16x8 pf = *(const bf16x8*)&P[cc * 56 + g * 8];
    #pragma unroll
    for (int dt = 0; dt < 4; dt++) {
      const u16t* vb = Vt + ((size_t)h * 64 + dt * 16 + cc) * N_SEQ + m0 + g * 8;
      bf16x8 vf = *(const bf16x8*)(vb);
      o[dt] = MFMA16(pf, vf, o[dt]);
    }
  }
  const int bb = h >> 4, hl = h & 15;
  #pragma unroll
  for (int r = 0; r < 4; r++) {
    const int q = q0 + g * 4 + r;
    float invL = 1.0f / L[r];
    const size_t orow = (size_t)(q * 2 + bb) * DSTR + hl * 64;
    #pragma unroll
    for (int dt = 0; dt < 4; dt++)
      Vals[orow + dt * 16 + cc] = f2bf(o[dt][r] * invL);
  }
}

// ---------------- GEMM 3: out = Vals @ w_out + b_out (plain bf16)
__global__ __launch_bounds__(256) void gemm_out_kernel(
    const u16t* __restrict__ A, const u16t* __restrict__ Bt,
    const float* __restrict__ bias, float* __restrict__ out) {
  constexpr int BM = 128, BK = 32, LDT = 40;
  __shared__ u16t sA[BM * LDT], sB[BM * LDT];
  const int t = threadIdx.x;
  const int lane = t & 63, wid = t >> 6;
  const int wm = wid >> 1, wn = wid & 1;
  const int g = lane >> 4, cc = lane & 15;
  const int m0 = blockIdx.x * BM, n0 = blockIdx.y * BM;
  const int srow = t >> 1, sseg = (t & 1) * 16;

  f32x4 acc[4][4] = {};
  for (int k0 = 0; k0 < DSTR; k0 += BK) {
    __syncthreads();
    *(bf16x8*)&sA[srow * LDT + sseg]     = *(const bf16x8*)(A + (size_t)(m0 + srow) * DSTR + k0 + sseg);
    *(bf16x8*)&sA[srow * LDT + sseg + 8] = *(const bf16x8*)(A + (size_t)(m0 + srow) * DSTR + k0 + sseg + 8);
    *(bf16x8*)&sB[srow * LDT + sseg]     = *(const bf16x8*)(Bt + (size_t)(n0 + srow) * DSTR + k0 + sseg);
    *(bf16x8*)&sB[srow * LDT + sseg + 8] = *(const bf16x8*)(Bt + (size_t)(n0 + srow) * DSTR + k0 + sseg + 8);
    __syncthreads();
    bf16x8 af[4], bfr[4];
    #pragma unroll
    for (int mt = 0; mt < 4; mt++)
      af[mt] = *(const bf16x8*)&sA[(wm * 64 + mt * 16 + cc) * LDT + g * 8];
    #pragma unroll
    for (int nt = 0; nt < 4; nt++)
      bfr[nt] = *(const bf16x8*)&sB[(wn * 64 + nt * 16 + cc) * LDT + g * 8];
    #pragma unroll
    for (int mt = 0; mt < 4; mt++)
      #pragma unroll
      for (int nt = 0; nt < 4; nt++)
        acc[mt][nt] = MFMA16(af[mt], bfr[nt], acc[mt][nt]);
  }
  #pragma unroll
  for (int mt = 0; mt < 4; mt++)
    #pragma unroll
    for (int nt = 0; nt < 4; nt++)
      #pragma unroll
      for (int r = 0; r < 4; r++) {
        int grow = m0 + wm * 64 + mt * 16 + g * 4 + r;
        int gcol = n0 + wn * 64 + nt * 16 + cc;
        out[(size_t)grow * DSTR + gcol] = acc[mt][nt][r] + bias[gcol];
      }
}

extern "C" void kernel_launch(void* const* d_in, const int* in_sizes, int n_in,
                              void* d_out, int out_size, void* d_ws, size_t ws_size,
                              hipStream_t stream) {
  (void)in_sizes; (void)n_in; (void)out_size; (void)ws_size;
  const float* x      = (const float*)d_in[0];
  const float* mask   = (const float*)d_in[1];
  const float* w_qkv  = (const float*)d_in[2];
  const float* b_qkv  = (const float*)d_in[3];
  const float* w_out  = (const float*)d_in[4];
  const float* b_out  = (const float*)d_in[5];
  float* out = (float*)d_out;

  char* ws = (char*)d_ws;
  size_t off = 0;
  auto alloc = [&](size_t n) { void* p = ws + off; off += (n + 255) & ~(size_t)255; return p; };
  u16t* WqkvThi = (u16t*)alloc((size_t)QKVN * DSTR * 2);
  u16t* WqkvTlo = (u16t*)alloc((size_t)QKVN * DSTR * 2);
  u16t* WoutT   = (u16t*)alloc((size_t)DSTR * DSTR * 2);
  u16t* Qhi = (u16t*)alloc((size_t)NH * N_SEQ * 64 * 2);
  u16t* Qlo = (u16t*)alloc((size_t)NH * N_SEQ * 64 * 2);
  u16t* Khi = (u16t*)alloc((size_t)NH * N_SEQ * 64 * 2);
  u16t* Klo = (u16t*)alloc((size_t)NH * N_SEQ * 64 * 2);
  u16t* Vt  = (u16t*)alloc((size_t)NH * 64 * N_SEQ * 2);
  u16t* Vals = (u16t*)alloc((size_t)MROWS * DSTR * 2);

  transpose_split_kernel<<<dim3(QKVN / 32, DSTR / 32), dim3(32, 8), 0, stream>>>(
      w_qkv, WqkvThi, WqkvTlo, DSTR, QKVN);
  transpose_split_kernel<<<dim3(DSTR / 32, DSTR / 32), dim3(32, 8), 0, stream>>>(
      w_out, WoutT, nullptr, DSTR, DSTR);
  gemm_qkv_kernel<<<dim3(MROWS / 128, QKVN / 128), 256, 0, stream>>>(
      x, WqkvThi, WqkvTlo, b_qkv, Qhi, Qlo, Khi, Klo, Vt);
  attn_kernel<<<dim3(NH * (N_SEQ / 64)), 256, 0, stream>>>(
      Qhi, Qlo, Khi, Klo, Vt, mask, Vals);
  gemm_out_kernel<<<dim3(MROWS / 128, DSTR / 128), 256, 0, stream>>>(
      Vals, WoutT, b_out, out);
}

// Round 2
// 339.546 us; speedup vs baseline: 1.8063x; 1.8063x over previous
//
#include <hip/hip_runtime.h>
#include <hip/hip_bf16.h>

#define N_SEQ 2048
#define DSTR 1024
#define NH 32          // B*HEADS
#define QKVN 3072      // HEADS*D_HEAD
#define MROWS 4096     // N*B

typedef float f32x4 __attribute__((ext_vector_type(4)));
typedef short bf16x8 __attribute__((ext_vector_type(8)));
typedef unsigned short ushort4v __attribute__((ext_vector_type(4)));
typedef unsigned short u16t;

__device__ __forceinline__ u16t f2bf(float f) {
  union { float f; unsigned u; } x; x.f = f;
  return (u16t)((x.u + 0x7fff + ((x.u >> 16) & 1)) >> 16);
}
__device__ __forceinline__ float bf2f(u16t u) {
  union { unsigned u; float f; } x; x.u = ((unsigned)u) << 16; return x.f;
}

#define MFMA16(a, b, c) __builtin_amdgcn_mfma_f32_16x16x32_bf16(a, b, c, 0, 0, 0)

__device__ __forceinline__ void gl2lds16(const void* g, void* l) {
  __builtin_amdgcn_global_load_lds((const __attribute__((address_space(1))) void*)g,
                                   (__attribute__((address_space(3))) void*)l, 16, 0, 0);
}

// ---------------- elementwise fp32 -> bf16 hi (+ optional lo), vectorized x4
__global__ void split_f32_kernel(const float* __restrict__ in, u16t* __restrict__ hi,
                                 u16t* __restrict__ lo, int n4) {
  int i = blockIdx.x * blockDim.x + threadIdx.x;
  if (i >= n4) return;
  float4 v = ((const float4*)in)[i];
  float vv[4] = {v.x, v.y, v.z, v.w};
  ushort4v h, l;
  #pragma unroll
  for (int j = 0; j < 4; j++) {
    h[j] = f2bf(vv[j]);
    l[j] = f2bf(vv[j] - bf2f(h[j]));
  }
  ((ushort4v*)hi)[i] = h;
  if (lo) ((ushort4v*)lo)[i] = l;
}

// ---------------- transpose + bf16 split: in fp32 [K][Nc] -> hi/lo bf16 [Nc][K]
__global__ void transpose_split_kernel(const float* __restrict__ in,
                                       u16t* __restrict__ hi, u16t* __restrict__ lo,
                                       int K, int Nc) {
  __shared__ float tile[32][33];
  const int n0 = blockIdx.x * 32, k0 = blockIdx.y * 32;
  const int tx = threadIdx.x, ty = threadIdx.y;
  #pragma unroll
  for (int j = 0; j < 32; j += 8)
    tile[ty + j][tx] = in[(size_t)(k0 + ty + j) * Nc + n0 + tx];
  __syncthreads();
  #pragma unroll
  for (int j = 0; j < 32; j += 8) {
    float v = tile[tx][ty + j];
    size_t o = (size_t)(n0 + ty + j) * K + k0 + tx;
    u16t h = f2bf(v);
    hi[o] = h;
    if (lo) lo[o] = f2bf(v - bf2f(h));
  }
}

// ---------------- GEMM 1: qkv = stream @ w_qkv + b_qkv, split-precision, reg-prefetch pipeline
__global__ __launch_bounds__(256) void gemm_qkv_kernel(
    const u16t* __restrict__ Ahi, const u16t* __restrict__ Alo,
    const u16t* __restrict__ Bhi, const u16t* __restrict__ Blo,
    const float* __restrict__ bias,
    u16t* __restrict__ Qhi, u16t* __restrict__ Qlo,
    u16t* __restrict__ Khi, u16t* __restrict__ Klo,
    u16t* __restrict__ Vt) {
  constexpr int BM = 128, BK = 32, LDT = 40;
  __shared__ u16t sAhi[BM * LDT], sAlo[BM * LDT], sBhi[BM * LDT], sBlo[BM * LDT];
  const int t = threadIdx.x;
  const int lane = t & 63, wid = t >> 6;
  const int wm = wid >> 1, wn = wid & 1;
  const int g = lane >> 4, cc = lane & 15;
  const int m0 = blockIdx.x * BM, n0 = blockIdx.y * BM;
  const int srow = t >> 1, sseg = (t & 1) * 16;

  const u16t* pAh = Ahi + (size_t)(m0 + srow) * DSTR + sseg;
  const u16t* pAl = Alo + (size_t)(m0 + srow) * DSTR + sseg;
  const u16t* pBh = Bhi + (size_t)(n0 + srow) * DSTR + sseg;
  const u16t* pBl = Blo + (size_t)(n0 + srow) * DSTR + sseg;

  bf16x8 rAh0, rAh1, rAl0, rAl1, rBh0, rBh1, rBl0, rBl1;
  auto ldregs = [&](int k0) {
    rAh0 = *(const bf16x8*)(pAh + k0); rAh1 = *(const bf16x8*)(pAh + k0 + 8);
    rAl0 = *(const bf16x8*)(pAl + k0); rAl1 = *(const bf16x8*)(pAl + k0 + 8);
    rBh0 = *(const bf16x8*)(pBh + k0); rBh1 = *(const bf16x8*)(pBh + k0 + 8);
    rBl0 = *(const bf16x8*)(pBl + k0); rBl1 = *(const bf16x8*)(pBl + k0 + 8);
  };
  ldregs(0);

  f32x4 acc[4][4] = {};
  for (int k0 = 0; k0 < DSTR; k0 += BK) {
    __syncthreads();
    *(bf16x8*)&sAhi[srow * LDT + sseg]     = rAh0;
    *(bf16x8*)&sAhi[srow * LDT + sseg + 8] = rAh1;
    *(bf16x8*)&sAlo[srow * LDT + sseg]     = rAl0;
    *(bf16x8*)&sAlo[srow * LDT + sseg + 8] = rAl1;
    *(bf16x8*)&sBhi[srow * LDT + sseg]     = rBh0;
    *(bf16x8*)&sBhi[srow * LDT + sseg + 8] = rBh1;
    *(bf16x8*)&sBlo[srow * LDT + sseg]     = rBl0;
    *(bf16x8*)&sBlo[srow * LDT + sseg + 8] = rBl1;
    __syncthreads();
    if (k0 + BK < DSTR) ldregs(k0 + BK);

    bf16x8 ah[4], al[4], bh[4], bl[4];
    #pragma unroll
    for (int mt = 0; mt < 4; mt++) {
      int r = wm * 64 + mt * 16 + cc;
      ah[mt] = *(const bf16x8*)&sAhi[r * LDT + g * 8];
      al[mt] = *(const bf16x8*)&sAlo[r * LDT + g * 8];
    }
    #pragma unroll
    for (int nt = 0; nt < 4; nt++) {
      int r = wn * 64 + nt * 16 + cc;
      bh[nt] = *(const bf16x8*)&sBhi[r * LDT + g * 8];
      bl[nt] = *(const bf16x8*)&sBlo[r * LDT + g * 8];
    }
    #pragma unroll
    for (int mt = 0; mt < 4; mt++)
      #pragma unroll
      for (int nt = 0; nt < 4; nt++) {
        acc[mt][nt] = MFMA16(ah[mt], bh[nt], acc[mt][nt]);
        acc[mt][nt] = MFMA16(al[mt], bh[nt], acc[mt][nt]);
        acc[mt][nt] = MFMA16(ah[mt], bl[nt], acc[mt][nt]);
      }
  }
  // epilogue: add bias, scatter into Qhi/Qlo/Khi/Klo/Vt
  #pragma unroll
  for (int mt = 0; mt < 4; mt++)
    #pragma unroll
    for (int nt = 0; nt < 4; nt++)
      #pragma unroll
      for (int r = 0; r < 4; r++) {
        int grow = m0 + wm * 64 + mt * 16 + g * 4 + r;
        int gcol = n0 + wn * 64 + nt * 16 + cc;
        float val = acc[mt][nt][r] + bias[gcol];
        int nn = grow >> 1, bb = grow & 1;
        int hl = gcol / 192, off = gcol - hl * 192;
        int hh = bb * 16 + hl;
        if (off < 64) {
          size_t o = ((size_t)hh * N_SEQ + nn) * 64 + off;
          u16t h_ = f2bf(val);
          Qhi[o] = h_;
          Qlo[o] = f2bf(val - bf2f(h_));
        } else if (off < 128) {
          size_t o = ((size_t)hh * N_SEQ + nn) * 64 + (off - 64);
          u16t h_ = f2bf(val);
          Khi[o] = h_;
          Klo[o] = f2bf(val - bf2f(h_));
        } else {
          Vt[((size_t)hh * 64 + (off - 128)) * N_SEQ + nn] = f2bf(val);
        }
      }
}

// ---------------- flash attention: 8 waves/block, KVBLK=64, LDS-staged K/V (async, dbuf, swizzled)
__global__ __launch_bounds__(512, 4) void attn_kernel(
    const u16t* __restrict__ Qhi, const u16t* __restrict__ Qlo,
    const u16t* __restrict__ Khi, const u16t* __restrict__ Klo,
    const u16t* __restrict__ Vt, const u16t* __restrict__ maskb,
    u16t* __restrict__ Vals) {
  __shared__ u16t sKh[2][64 * 64];
  __shared__ u16t sKl[2][64 * 64];
  __shared__ u16t sV[2][64 * 64];
  __shared__ u16t sP[8][16 * 72];
  const int t = threadIdx.x;
  const int lane = t & 63, wid = t >> 6;
  const int g = lane >> 4, cc = lane & 15;
  const int h = blockIdx.x >> 4;
  const int qt = blockIdx.x & 15;
  const int q0 = qt * 128 + wid * 16;

  const size_t kbase = (size_t)h * N_SEQ * 64;
  const size_t vbase = (size_t)h * 64 * N_SEQ;

  // staging geometry: thread t stages 16B; slot row = t>>3, chunk = t&7,
  // source chunk inverse-XOR-swizzled so swizzled reads see linear data
  const int srow = t >> 3;
  const int ssw = ((t & 7) ^ (srow & 7)) * 8;
  const int wbase = wid * 512;  // wave-uniform LDS dest (u16 units)

  auto stage = [&](int buf, int m0) {
    gl2lds16(Khi + kbase + (size_t)(m0 + srow) * 64 + ssw, &sKh[buf][wbase]);
    gl2lds16(Klo + kbase + (size_t)(m0 + srow) * 64 + ssw, &sKl[buf][wbase]);
    gl2lds16(Vt + vbase + (size_t)srow * N_SEQ + m0 + ssw, &sV[buf][wbase]);
  };

  const size_t qoff = kbase + (size_t)(q0 + cc) * 64 + g * 8;
  bf16x8 qh0 = *(const bf16x8*)(Qhi + qoff);
  bf16x8 qh1 = *(const bf16x8*)(Qhi + qoff + 32);
  bf16x8 ql0 = *(const bf16x8*)(Qlo + qoff);
  bf16x8 ql1 = *(const bf16x8*)(Qlo + qoff + 32);

  f32x4 o[4] = {};
  float M[4], L[4];
  #pragma unroll
  for (int r = 0; r < 4; r++) { M[r] = -1e30f; L[r] = 0.0f; }

  stage(0, 0);
  int cur = 0;
  const int sw = (cc & 7) * 8;

  for (int ti = 0; ti < N_SEQ / 64; ++ti) {
    const int m0 = ti * 64;
    __syncthreads();  // drains vmcnt: staging of buf[cur] complete; all waves off buf[cur^1]
    if (ti + 1 < N_SEQ / 64) stage(cur ^ 1, m0 + 64);

    // mask prefetch (bf16, kept packed)
    u16t mreg[4][4];
    #pragma unroll
    for (int mt = 0; mt < 4; ++mt)
      #pragma unroll
      for (int r = 0; r < 4; ++r)
        mreg[mt][r] = maskb[(size_t)(q0 + g * 4 + r) * N_SEQ + m0 + mt * 16 + cc];

    f32x4 s[4];
    #pragma unroll
    for (int mt = 0; mt < 4; ++mt) {
      const int krow = (mt * 16 + cc) * 64;
      bf16x8 kh0 = *(const bf16x8*)&sKh[cur][krow + ((g * 8) ^ sw)];
      bf16x8 kh1 = *(const bf16x8*)&sKh[cur][krow + ((32 + g * 8) ^ sw)];
      bf16x8 kl0 = *(const bf16x8*)&sKl[cur][krow + ((g * 8) ^ sw)];
      bf16x8 kl1 = *(const bf16x8*)&sKl[cur][krow + ((32 + g * 8) ^ sw)];
      f32x4 a = {};
      a = MFMA16(qh0, kh0, a);
      a = MFMA16(qh1, kh1, a);
      a = MFMA16(ql0, kh0, a);
      a = MFMA16(ql1, kh1, a);
      a = MFMA16(qh0, kl0, a);
      a = MFMA16(qh1, kl1, a);
      s[mt] = a;
    }
    #pragma unroll
    for (int r = 0; r < 4; ++r) {
      s[0][r] += bf2f(mreg[0][r]);
      s[1][r] += bf2f(mreg[1][r]);
      s[2][r] += bf2f(mreg[2][r]);
      s[3][r] += bf2f(mreg[3][r]);
      float mx = fmaxf(fmaxf(s[0][r], s[1][r]), fmaxf(s[2][r], s[3][r]));
      mx = fmaxf(mx, __shfl_xor(mx, 1, 16));
      mx = fmaxf(mx, __shfl_xor(mx, 2, 16));
      mx = fmaxf(mx, __shfl_xor(mx, 4, 16));
      mx = fmaxf(mx, __shfl_xor(mx, 8, 16));
      float newM = fmaxf(M[r], mx);
      float alpha = __expf(M[r] - newM);
      float p0 = __expf(s[0][r] - newM);
      float p1 = __expf(s[1][r] - newM);
      float p2 = __expf(s[2][r] - newM);
      float p3 = __expf(s[3][r] - newM);
      float rs = (p0 + p1) + (p2 + p3);
      rs += __shfl_xor(rs, 1, 16);
      rs += __shfl_xor(rs, 2, 16);
      rs += __shfl_xor(rs, 4, 16);
      rs += __shfl_xor(rs, 8, 16);
      L[r] = L[r] * alpha + rs;
      M[r] = newM;
      o[0][r] *= alpha; o[1][r] *= alpha; o[2][r] *= alpha; o[3][r] *= alpha;
      u16t* P = &sP[wid][(g * 4 + r) * 72];
      P[cc]      = f2bf(p0);
      P[16 + cc] = f2bf(p1);
      P[32 + cc] = f2bf(p2);
      P[48 + cc] = f2bf(p3);
    }
    bf16x8 pf0 = *(const bf16x8*)&sP[wid][cc * 72 + g * 8];
    bf16x8 pf1 = *(const bf16x8*)&sP[wid][cc * 72 + 32 + g * 8];
    #pragma unroll
    for (int dt = 0; dt < 4; ++dt) {
      const int vrow = (dt * 16 + cc) * 64;
      bf16x8 v0 = *(const bf16x8*)&sV[cur][vrow + ((g * 8) ^ sw)];
      bf16x8 v1 = *(const bf16x8*)&sV[cur][vrow + ((32 + g * 8) ^ sw)];
      o[dt] = MFMA16(pf0, v0, o[dt]);
      o[dt] = MFMA16(pf1, v1, o[dt]);
    }
    cur ^= 1;
  }
  const int bb = h >> 4, hl = h & 15;
  #pragma unroll
  for (int r = 0; r < 4; ++r) {
    const int q = q0 + g * 4 + r;
    float invL = 1.0f / L[r];
    const size_t orow = (size_t)(q * 2 + bb) * DSTR + hl * 64;
    #pragma unroll
    for (int dt = 0; dt < 4; ++dt)
      Vals[orow + dt * 16 + cc] = f2bf(o[dt][r] * invL);
  }
}

// ---------------- GEMM 3: out = Vals @ w_out + b_out (plain bf16), reg-prefetch pipeline
__global__ __launch_bounds__(256) void gemm_out_kernel(
    const u16t* __restrict__ A, const u16t* __restrict__ Bt,
    const float* __restrict__ bias, float* __restrict__ out) {
  constexpr int BM = 128, BK = 32, LDT = 40;
  __shared__ u16t sA[BM * LDT], sB[BM * LDT];
  const int t = threadIdx.x;
  const int lane = t & 63, wid = t >> 6;
  const int wm = wid >> 1, wn = wid & 1;
  const int g = lane >> 4, cc = lane & 15;
  const int m0 = blockIdx.x * BM, n0 = blockIdx.y * BM;
  const int srow = t >> 1, sseg = (t & 1) * 16;

  const u16t* pA = A + (size_t)(m0 + srow) * DSTR + sseg;
  const u16t* pB = Bt + (size_t)(n0 + srow) * DSTR + sseg;
  bf16x8 rA0, rA1, rB0, rB1;
  auto ldregs = [&](int k0) {
    rA0 = *(const bf16x8*)(pA + k0); rA1 = *(const bf16x8*)(pA + k0 + 8);
    rB0 = *(const bf16x8*)(pB + k0); rB1 = *(const bf16x8*)(pB + k0 + 8);
  };
  ldregs(0);

  f32x4 acc[4][4] = {};
  for (int k0 = 0; k0 < DSTR; k0 += BK) {
    __syncthreads();
    *(bf16x8*)&sA[srow * LDT + sseg]     = rA0;
    *(bf16x8*)&sA[srow * LDT + sseg + 8] = rA1;
    *(bf16x8*)&sB[srow * LDT + sseg]     = rB0;
    *(bf16x8*)&sB[srow * LDT + sseg + 8] = rB1;
    __syncthreads();
    if (k0 + BK < DSTR) ldregs(k0 + BK);

    bf16x8 af[4], bfr[4];
    #pragma unroll
    for (int mt = 0; mt < 4; mt++)
      af[mt] = *(const bf16x8*)&sA[(wm * 64 + mt * 16 + cc) * LDT + g * 8];
    #pragma unroll
    for (int nt = 0; nt < 4; nt++)
      bfr[nt] = *(const bf16x8*)&sB[(wn * 64 + nt * 16 + cc) * LDT + g * 8];
    #pragma unroll
    for (int mt = 0; mt < 4; mt++)
      #pragma unroll
      for (int nt = 0; nt < 4; nt++)
        acc[mt][nt] = MFMA16(af[mt], bfr[nt], acc[mt][nt]);
  }
  #pragma unroll
  for (int mt = 0; mt < 4; mt++)
    #pragma unroll
    for (int nt = 0; nt < 4; nt++)
      #pragma unroll
      for (int r = 0; r < 4; r++) {
        int grow = m0 + wm * 64 + mt * 16 + g * 4 + r;
        int gcol = n0 + wn * 64 + nt * 16 + cc;
        out[(size_t)grow * DSTR + gcol] = acc[mt][nt][r] + bias[gcol];
      }
}

extern "C" void kernel_launch(void* const* d_in, const int* in_sizes, int n_in,
                              void* d_out, int out_size, void* d_ws, size_t ws_size,
                              hipStream_t stream) {
  (void)in_sizes; (void)n_in; (void)out_size; (void)ws_size;
  const float* x      = (const float*)d_in[0];
  const float* mask   = (const float*)d_in[1];
  const float* w_qkv  = (const float*)d_in[2];
  const float* b_qkv  = (const float*)d_in[3];
  const float* w_out  = (const float*)d_in[4];
  const float* b_out  = (const float*)d_in[5];
  float* out = (float*)d_out;

  char* ws = (char*)d_ws;
  size_t off = 0;
  auto alloc = [&](size_t n) { void* p = ws + off; off += (n + 255) & ~(size_t)255; return p; };
  u16t* WqkvThi = (u16t*)alloc((size_t)QKVN * DSTR * 2);
  u16t* WqkvTlo = (u16t*)alloc((size_t)QKVN * DSTR * 2);
  u16t* WoutT   = (u16t*)alloc((size_t)DSTR * DSTR * 2);
  u16t* Qhi = (u16t*)alloc((size_t)NH * N_SEQ * 64 * 2);
  u16t* Qlo = (u16t*)alloc((size_t)NH * N_SEQ * 64 * 2);
  u16t* Khi = (u16t*)alloc((size_t)NH * N_SEQ * 64 * 2);
  u16t* Klo = (u16t*)alloc((size_t)NH * N_SEQ * 64 * 2);
  u16t* Vt  = (u16t*)alloc((size_t)NH * 64 * N_SEQ * 2);
  u16t* Xhi = (u16t*)alloc((size_t)MROWS * DSTR * 2);  // reused as Vals after gemm_qkv
  u16t* Xlo = (u16t*)alloc((size_t)MROWS * DSTR * 2);
  u16t* Maskb = (u16t*)alloc((size_t)N_SEQ * N_SEQ * 2);
  u16t* Vals = Xhi;  // alias: X consumed by gemm_qkv before attn writes Vals

  split_f32_kernel<<<dim3(MROWS * DSTR / 4 / 256), 256, 0, stream>>>(x, Xhi, Xlo, MROWS * DSTR / 4);
  split_f32_kernel<<<dim3(N_SEQ * N_SEQ / 4 / 256), 256, 0, stream>>>(mask, Maskb, nullptr, N_SEQ * N_SEQ / 4);
  transpose_split_kernel<<<dim3(QKVN / 32, DSTR / 32), dim3(32, 8), 0, stream>>>(
      w_qkv, WqkvThi, WqkvTlo, DSTR, QKVN);
  transpose_split_kernel<<<dim3(DSTR / 32, DSTR / 32), dim3(32, 8), 0, stream>>>(
      w_out, WoutT, nullptr, DSTR, DSTR);
  gemm_qkv_kernel<<<dim3(MROWS / 128, QKVN / 128), 256, 0, stream>>>(
      Xhi, Xlo, WqkvThi, WqkvTlo, b_qkv, Qhi, Qlo, Khi, Klo, Vt);
  attn_kernel<<<dim3(NH * (N_SEQ / 128)), 512, 0, stream>>>(
      Qhi, Qlo, Khi, Klo, Vt, Maskb, Vals);
  gemm_out_kernel<<<dim3(MROWS / 128, DSTR / 128), 256, 0, stream>>>(
      Vals, WoutT, b_out, out);
}

// Round 6
// 272.773 us; speedup vs baseline: 2.2485x; 1.2448x over previous
//
#include <hip/hip_runtime.h>
#include <hip/hip_bf16.h>

#define N_SEQ 2048
#define DSTR 1024
#define NH 32          // B*HEADS
#define QKVN 3072      // HEADS*D_HEAD
#define MROWS 4096     // N*B

typedef float f32x4 __attribute__((ext_vector_type(4)));
typedef short bf16x8 __attribute__((ext_vector_type(8)));
typedef unsigned short ushort4v __attribute__((ext_vector_type(4)));
typedef unsigned short u16t;

__device__ __forceinline__ u16t f2bf(float f) {
  union { float f; unsigned u; } x; x.f = f;
  return (u16t)((x.u + 0x7fff + ((x.u >> 16) & 1)) >> 16);
}
__device__ __forceinline__ float bf2f(u16t u) {
  union { unsigned u; float f; } x; x.u = ((unsigned)u) << 16; return x.f;
}
// packs bf16(a) into low 16, bf16(b) into high 16 (RNE)
__device__ __forceinline__ unsigned cvt_pk_bf16(float a, float b) {
  unsigned r;
  asm("v_cvt_pk_bf16_f32 %0, %1, %2" : "=v"(r) : "v"(a), "v"(b));
  return r;
}

#define MFMA16(a, b, c) __builtin_amdgcn_mfma_f32_16x16x32_bf16(a, b, c, 0, 0, 0)

__device__ __forceinline__ void gl2lds16(const void* g, void* l) {
  __builtin_amdgcn_global_load_lds((const __attribute__((address_space(1))) void*)g,
                                   (__attribute__((address_space(3))) void*)l, 16, 0, 0);
}

// ---------------- elementwise fp32 -> bf16 hi (+ optional lo), vectorized x4
__global__ void split_f32_kernel(const float* __restrict__ in, u16t* __restrict__ hi,
                                 u16t* __restrict__ lo, int n4) {
  int i = blockIdx.x * blockDim.x + threadIdx.x;
  if (i >= n4) return;
  float4 v = ((const float4*)in)[i];
  float vv[4] = {v.x, v.y, v.z, v.w};
  ushort4v h, l;
  #pragma unroll
  for (int j = 0; j < 4; j++) {
    h[j] = f2bf(vv[j]);
    l[j] = f2bf(vv[j] - bf2f(h[j]));
  }
  ((ushort4v*)hi)[i] = h;
  if (lo) ((ushort4v*)lo)[i] = l;
}

// ---------------- transpose (+ optional lo split): in fp32 [K][Nc] -> bf16 [Nc][K]
__global__ void transpose_split_kernel(const float* __restrict__ in,
                                       u16t* __restrict__ hi, u16t* __restrict__ lo,
                                       int K, int Nc) {
  __shared__ float tile[32][33];
  const int n0 = blockIdx.x * 32, k0 = blockIdx.y * 32;
  const int tx = threadIdx.x, ty = threadIdx.y;
  #pragma unroll
  for (int j = 0; j < 32; j += 8)
    tile[ty + j][tx] = in[(size_t)(k0 + ty + j) * Nc + n0 + tx];
  __syncthreads();
  #pragma unroll
  for (int j = 0; j < 32; j += 8) {
    float v = tile[tx][ty + j];
    size_t o = (size_t)(n0 + ty + j) * K + k0 + tx;
    u16t h = f2bf(v);
    hi[o] = h;
    if (lo) lo[o] = f2bf(v - bf2f(h));
  }
}

// ---------------- GEMM 1: qkv = stream @ w_qkv + b_qkv
// A split hi/lo (2 MFMA streams), B hi only. m97-style: BK=64, global_load_lds
// w16, XOR-swizzled source + swizzled ds_read_b128, single-buffered 2-barrier loop.
__global__ __launch_bounds__(256, 3) void gemm_qkv_kernel(
    const u16t* __restrict__ Ahi, const u16t* __restrict__ Alo,
    const u16t* __restrict__ Bhi, const float* __restrict__ bias,
    u16t* __restrict__ Qhi, u16t* __restrict__ Qlo,
    u16t* __restrict__ Khi, u16t* __restrict__ Vt) {
  constexpr int BK = 64;
  __shared__ u16t sAh[128 * 64], sAl[128 * 64], sBh[128 * 64];
  const int t = threadIdx.x;
  const int lane = t & 63, wid = t >> 6;
  const int wm = wid >> 1, wn = wid & 1;
  const int g = lane >> 4, cc = lane & 15;
  const int m0 = blockIdx.x * 128, n0 = blockIdx.y * 128;
  const int srow = t >> 3;                           // 0..31 (+32 per iter)
  const int sc = ((t & 7) ^ ((t >> 3) & 7)) * 8;     // swizzled source chunk (u16)

  f32x4 acc[4][4] = {};

  for (int k0 = 0; k0 < DSTR; k0 += BK) {
    __syncthreads();
    #pragma unroll
    for (int i = 0; i < 4; i++) {
      const int row = i * 32 + srow;
      // LDS dest: wave-uniform base; HW places lane l at base + l*16B
      gl2lds16(Ahi + (size_t)(m0 + row) * DSTR + k0 + sc, &sAh[i * 2048 + wid * 512]);
      gl2lds16(Alo + (size_t)(m0 + row) * DSTR + k0 + sc, &sAl[i * 2048 + wid * 512]);
      gl2lds16(Bhi + (size_t)(n0 + row) * DSTR + k0 + sc, &sBh[i * 2048 + wid * 512]);
    }
    __syncthreads();
    #pragma unroll
    for (int kk = 0; kk < 2; kk++) {
      bf16x8 ah[4], al[4], bh[4];
      #pragma unroll
      for (int mt = 0; mt < 4; mt++) {
        const int r = wm * 64 + mt * 16 + cc;
        const int c = ((4 * kk + g) ^ (cc & 7)) * 8;
        ah[mt] = *(const bf16x8*)&sAh[r * 64 + c];
        al[mt] = *(const bf16x8*)&sAl[r * 64 + c];
      }
      #pragma unroll
      for (int nt = 0; nt < 4; nt++) {
        const int r = wn * 64 + nt * 16 + cc;
        const int c = ((4 * kk + g) ^ (cc & 7)) * 8;
        bh[nt] = *(const bf16x8*)&sBh[r * 64 + c];
      }
      #pragma unroll
      for (int mt = 0; mt < 4; mt++)
        #pragma unroll
        for (int nt = 0; nt < 4; nt++) {
          acc[mt][nt] = MFMA16(ah[mt], bh[nt], acc[mt][nt]);
          acc[mt][nt] = MFMA16(al[mt], bh[nt], acc[mt][nt]);
        }
    }
  }
  // epilogue: bias, scatter to Qhi/Qlo/Khi and key-permuted Vt
  #pragma unroll
  for (int mt = 0; mt < 4; mt++)
    #pragma unroll
    for (int nt = 0; nt < 4; nt++)
      #pragma unroll
      for (int r = 0; r < 4; r++) {
        int grow = m0 + wm * 64 + mt * 16 + g * 4 + r;
        int gcol = n0 + wn * 64 + nt * 16 + cc;
        float val = acc[mt][nt][r] + bias[gcol];
        int nn = grow >> 1, bb = grow & 1;
        int hl = gcol / 192, off = gcol - hl * 192;
        int hh = bb * 16 + hl;
        if (off < 64) {
          size_t o = ((size_t)hh * N_SEQ + nn) * 64 + off;
          u16t h_ = f2bf(val);
          Qhi[o] = h_;
          Qlo[o] = f2bf(val - bf2f(h_));
        } else if (off < 128) {
          Khi[((size_t)hh * N_SEQ + nn) * 64 + (off - 64)] = f2bf(val);
        } else {
          // key-permuted V: tile pos c -> c' = ((c&15)<<2)|(c>>4)
          int c = nn & 63;
          int nperm = (nn & ~63) | ((c & 15) << 2) | (c >> 4);
          Vt[((size_t)hh * 64 + (off - 128)) * N_SEQ + nperm] = f2bf(val);
        }
      }
}

// ---------------- flash attention: 8 waves, KVBLK=64, dbuf LDS K/V,
// Q-side lo compensation only, transposed bf16 mask, defer-max,
// permuted-key P store (cvt_pk words -> scalar u16 stores: alias-safe).
__global__ __launch_bounds__(512, 4) void attn_kernel(
    const u16t* __restrict__ Qhi, const u16t* __restrict__ Qlo,
    const u16t* __restrict__ Khi, const u16t* __restrict__ Vt,
    const u16t* __restrict__ maskT, u16t* __restrict__ Vals) {
  __shared__ u16t sKh[2][64 * 64];
  __shared__ u16t sV[2][64 * 64];
  __shared__ u16t sP[8][16 * 72];
  const int t = threadIdx.x;
  const int lane = t & 63, wid = t >> 6;
  const int g = lane >> 4, cc = lane & 15;
  const int h = blockIdx.x >> 4;
  const int qt = blockIdx.x & 15;
  const int q0 = qt * 128 + wid * 16;

  const size_t kbase = (size_t)h * N_SEQ * 64;
  const size_t vbase = (size_t)h * 64 * N_SEQ;

  const int srow = t >> 3;
  const int ssw = ((t & 7) ^ (srow & 7)) * 8;
  const int wbase = wid * 512;

  auto stage = [&](int buf, int mt0) {
    gl2lds16(Khi + kbase + (size_t)(mt0 + srow) * 64 + ssw, &sKh[buf][wbase]);
    gl2lds16(Vt + vbase + (size_t)srow * N_SEQ + mt0 + ssw, &sV[buf][wbase]);
  };

  const size_t qoff = kbase + (size_t)(q0 + cc) * 64 + g * 8;
  bf16x8 qh0 = *(const bf16x8*)(Qhi + qoff);
  bf16x8 qh1 = *(const bf16x8*)(Qhi + qoff + 32);
  bf16x8 ql0 = *(const bf16x8*)(Qlo + qoff);
  bf16x8 ql1 = *(const bf16x8*)(Qlo + qoff + 32);

  f32x4 o[4] = {};
  float M[4], L[4];
  #pragma unroll
  for (int r = 0; r < 4; r++) { M[r] = -1e30f; L[r] = 0.0f; }

  stage(0, 0);
  int cur = 0;
  const int sw = (cc & 7) * 8;

  for (int ti = 0; ti < N_SEQ / 64; ++ti) {
    const int mt0 = ti * 64;
    __syncthreads();  // staging of buf[cur] complete; all waves off buf[cur^1]
    if (ti + 1 < N_SEQ / 64) stage(cur ^ 1, mt0 + 64);

    // transposed mask: 4 x b64 loads, each = 4 bf16 for r=0..3
    ushort4v ml[4];
    #pragma unroll
    for (int mt = 0; mt < 4; ++mt)
      ml[mt] = *(const ushort4v*)&maskT[(size_t)(mt0 + mt * 16 + cc) * N_SEQ + q0 + g * 4];

    f32x4 s[4];
    #pragma unroll
    for (int mt = 0; mt < 4; ++mt) {
      const int krow = (mt * 16 + cc) * 64;
      bf16x8 kh0 = *(const bf16x8*)&sKh[cur][krow + ((g * 8) ^ sw)];
      bf16x8 kh1 = *(const bf16x8*)&sKh[cur][krow + ((32 + g * 8) ^ sw)];
      f32x4 a = {};
      a = MFMA16(qh0, kh0, a);
      a = MFMA16(qh1, kh1, a);
      a = MFMA16(ql0, kh0, a);
      a = MFMA16(ql1, kh1, a);
      s[mt] = a;
    }
    float mx[4];
    #pragma unroll
    for (int r = 0; r < 4; ++r) {
      s[0][r] += bf2f(ml[0][r]);
      s[1][r] += bf2f(ml[1][r]);
      s[2][r] += bf2f(ml[2][r]);
      s[3][r] += bf2f(ml[3][r]);
      float m1 = fmaxf(fmaxf(s[0][r], s[1][r]), fmaxf(s[2][r], s[3][r]));
      m1 = fmaxf(m1, __shfl_xor(m1, 1, 16));
      m1 = fmaxf(m1, __shfl_xor(m1, 2, 16));
      m1 = fmaxf(m1, __shfl_xor(m1, 4, 16));
      m1 = fmaxf(m1, __shfl_xor(m1, 8, 16));
      mx[r] = m1;
    }
    float dm = fmaxf(fmaxf(mx[0] - M[0], mx[1] - M[1]),
                     fmaxf(mx[2] - M[2], mx[3] - M[3]));
    if (__any(dm > 8.0f)) {  // rescale only when running max moved materially
      #pragma unroll
      for (int r = 0; r < 4; ++r) {
        float nM = fmaxf(M[r], mx[r]);
        float al = __expf(M[r] - nM);
        L[r] *= al;
        o[0][r] *= al; o[1][r] *= al; o[2][r] *= al; o[3][r] *= al;
        M[r] = nM;
      }
    }
    #pragma unroll
    for (int r = 0; r < 4; ++r) {
      float p0 = __expf(s[0][r] - M[r]);
      float p1 = __expf(s[1][r] - M[r]);
      float p2 = __expf(s[2][r] - M[r]);
      float p3 = __expf(s[3][r] - M[r]);
      float rs = (p0 + p1) + (p2 + p3);
      rs += __shfl_xor(rs, 1, 16);
      rs += __shfl_xor(rs, 2, 16);
      rs += __shfl_xor(rs, 4, 16);
      rs += __shfl_xor(rs, 8, 16);
      L[r] += rs;
      // permuted-key P store: cols cc*4+{0..3} hold (p0,p1,p2,p3).
      // Scalar u16 stores (same elemental type as the bf16x8 read below):
      // avoids the uint2-pun TBAA reordering that broke the previous round.
      unsigned w0 = cvt_pk_bf16(p0, p1);
      unsigned w1 = cvt_pk_bf16(p2, p3);
      u16t* P = &sP[wid][(g * 4 + r) * 72 + cc * 4];
      P[0] = (u16t)w0; P[1] = (u16t)(w0 >> 16);
      P[2] = (u16t)w1; P[3] = (u16t)(w1 >> 16);
    }
    bf16x8 pf0 = *(const bf16x8*)&sP[wid][cc * 72 + g * 8];
    bf16x8 pf1 = *(const bf16x8*)&sP[wid][cc * 72 + 32 + g * 8];
    #pragma unroll
    for (int dt = 0; dt < 4; ++dt) {
      const int vrow = (dt * 16 + cc) * 64;
      bf16x8 v0 = *(const bf16x8*)&sV[cur][vrow + ((g * 8) ^ sw)];
      bf16x8 v1 = *(const bf16x8*)&sV[cur][vrow + ((32 + g * 8) ^ sw)];
      o[dt] = MFMA16(pf0, v0, o[dt]);
      o[dt] = MFMA16(pf1, v1, o[dt]);
    }
    cur ^= 1;
  }
  const int bb = h >> 4, hl = h & 15;
  #pragma unroll
  for (int r = 0; r < 4; ++r) {
    const int q = q0 + g * 4 + r;
    float invL = 1.0f / L[r];
    const size_t orow = (size_t)(q * 2 + bb) * DSTR + hl * 64;
    #pragma unroll
    for (int dt = 0; dt < 4; ++dt)
      Vals[orow + dt * 16 + cc] = f2bf(o[dt][r] * invL);
  }
}

// ---------------- GEMM 3: out = Vals @ w_out + b_out (plain bf16, m97-style)
__global__ __launch_bounds__(256, 3) void gemm_out_kernel(
    const u16t* __restrict__ A, const u16t* __restrict__ Bt,
    const float* __restrict__ bias, float* __restrict__ out) {
  constexpr int BK = 64;
  __shared__ u16t sA[128 * 64], sB[128 * 64];
  const int t = threadIdx.x;
  const int lane = t & 63, wid = t >> 6;
  const int wm = wid >> 1, wn = wid & 1;
  const int g = lane >> 4, cc = lane & 15;
  const int m0 = blockIdx.x * 128, n0 = blockIdx.y * 128;
  const int srow = t >> 3;
  const int sc = ((t & 7) ^ ((t >> 3) & 7)) * 8;

  f32x4 acc[4][4] = {};
  for (int k0 = 0; k0 < DSTR; k0 += BK) {
    __syncthreads();
    #pragma unroll
    for (int i = 0; i < 4; i++) {
      const int row = i * 32 + srow;
      gl2lds16(A + (size_t)(m0 + row) * DSTR + k0 + sc, &sA[i * 2048 + wid * 512]);
      gl2lds16(Bt + (size_t)(n0 + row) * DSTR + k0 + sc, &sB[i * 2048 + wid * 512]);
    }
    __syncthreads();
    #pragma unroll
    for (int kk = 0; kk < 2; kk++) {
      bf16x8 af[4], bfr[4];
      #pragma unroll
      for (int mt = 0; mt < 4; mt++) {
        const int r = wm * 64 + mt * 16 + cc;
        const int c = ((4 * kk + g) ^ (cc & 7)) * 8;
        af[mt] = *(const bf16x8*)&sA[r * 64 + c];
      }
      #pragma unroll
      for (int nt = 0; nt < 4; nt++) {
        const int r = wn * 64 + nt * 16 + cc;
        const int c = ((4 * kk + g) ^ (cc & 7)) * 8;
        bfr[nt] = *(const bf16x8*)&sB[r * 64 + c];
      }
      #pragma unroll
      for (int mt = 0; mt < 4; mt++)
        #pragma unroll
        for (int nt = 0; nt < 4; nt++)
          acc[mt][nt] = MFMA16(af[mt], bfr[nt], acc[mt][nt]);
    }
  }
  #pragma unroll
  for (int mt = 0; mt < 4; mt++)
    #pragma unroll
    for (int nt = 0; nt < 4; nt++)
      #pragma unroll
      for (int r = 0; r < 4; r++) {
        int grow = m0 + wm * 64 + mt * 16 + g * 4 + r;
        int gcol = n0 + wn * 64 + nt * 16 + cc;
        out[(size_t)grow * DSTR + gcol] = acc[mt][nt][r] + bias[gcol];
      }
}

extern "C" void kernel_launch(void* const* d_in, const int* in_sizes, int n_in,
                              void* d_out, int out_size, void* d_ws, size_t ws_size,
                              hipStream_t stream) {
  (void)in_sizes; (void)n_in; (void)out_size; (void)ws_size;
  const float* x      = (const float*)d_in[0];
  const float* mask   = (const float*)d_in[1];
  const float* w_qkv  = (const float*)d_in[2];
  const float* b_qkv  = (const float*)d_in[3];
  const float* w_out  = (const float*)d_in[4];
  const float* b_out  = (const float*)d_in[5];
  float* out = (float*)d_out;

  char* ws = (char*)d_ws;
  size_t off = 0;
  auto alloc = [&](size_t n) { void* p = ws + off; off += (n + 255) & ~(size_t)255; return p; };
  u16t* WqkvT = (u16t*)alloc((size_t)QKVN * DSTR * 2);
  u16t* WoutT = (u16t*)alloc((size_t)DSTR * DSTR * 2);
  u16t* Qhi = (u16t*)alloc((size_t)NH * N_SEQ * 64 * 2);
  u16t* Qlo = (u16t*)alloc((size_t)NH * N_SEQ * 64 * 2);
  u16t* Khi = (u16t*)alloc((size_t)NH * N_SEQ * 64 * 2);
  u16t* Vt  = (u16t*)alloc((size_t)NH * 64 * N_SEQ * 2);
  u16t* Xhi = (u16t*)alloc((size_t)MROWS * DSTR * 2);  // reused as Vals after gemm_qkv
  u16t* Xlo = (u16t*)alloc((size_t)MROWS * DSTR * 2);
  u16t* MaskT = (u16t*)alloc((size_t)N_SEQ * N_SEQ * 2);
  u16t* Vals = Xhi;  // alias: X consumed by gemm_qkv before attn writes Vals

  split_f32_kernel<<<dim3(MROWS * DSTR / 4 / 256), 256, 0, stream>>>(x, Xhi, Xlo, MROWS * DSTR / 4);
  transpose_split_kernel<<<dim3(QKVN / 32, DSTR / 32), dim3(32, 8), 0, stream>>>(
      w_qkv, WqkvT, nullptr, DSTR, QKVN);
  transpose_split_kernel<<<dim3(DSTR / 32, DSTR / 32), dim3(32, 8), 0, stream>>>(
      w_out, WoutT, nullptr, DSTR, DSTR);
  transpose_split_kernel<<<dim3(N_SEQ / 32, N_SEQ / 32), dim3(32, 8), 0, stream>>>(
      mask, MaskT, nullptr, N_SEQ, N_SEQ);
  gemm_qkv_kernel<<<dim3(MROWS / 128, QKVN / 128), 256, 0, stream>>>(
      Xhi, Xlo, WqkvT, b_qkv, Qhi, Qlo, Khi, Vt);
  attn_kernel<<<dim3(NH * (N_SEQ / 128)), 512, 0, stream>>>(
      Qhi, Qlo, Khi, Vt, MaskT, Vals);
  gemm_out_kernel<<<dim3(MROWS / 128, DSTR / 128), 256, 0, stream>>>(
      Vals, WoutT, b_out, out);
}

// Round 8
// 266.300 us; speedup vs baseline: 2.3032x; 1.0243x over previous
//
#include <hip/hip_runtime.h>
#include <hip/hip_bf16.h>

#define N_SEQ 2048
#define DSTR 1024
#define NH 32          // B*HEADS
#define QKVN 3072      // HEADS*D_HEAD
#define MROWS 4096     // N*B
#define LOG2E 1.4426950408889634f

typedef float f32x4 __attribute__((ext_vector_type(4)));
typedef short bf16x8 __attribute__((ext_vector_type(8)));
typedef unsigned short ushort4v __attribute__((ext_vector_type(4)));
typedef unsigned short u16t;

__device__ __forceinline__ u16t f2bf(float f) {
  union { float f; unsigned u; } x; x.f = f;
  return (u16t)((x.u + 0x7fff + ((x.u >> 16) & 1)) >> 16);
}
__device__ __forceinline__ float bf2f(u16t u) {
  union { unsigned u; float f; } x; x.u = ((unsigned)u) << 16; return x.f;
}
// packs bf16(a) into low 16, bf16(b) into high 16 (RNE)
__device__ __forceinline__ unsigned cvt_pk_bf16(float a, float b) {
  unsigned r;
  asm("v_cvt_pk_bf16_f32 %0, %1, %2" : "=v"(r) : "v"(a), "v"(b));
  return r;
}
// 2^x via v_exp_f32 (pure, schedulable)
__device__ __forceinline__ float exp2a(float x) {
  float r;
  asm("v_exp_f32 %0, %1" : "=v"(r) : "v"(x));
  return r;
}

#define MFMA16(a, b, c) __builtin_amdgcn_mfma_f32_16x16x32_bf16(a, b, c, 0, 0, 0)

__device__ __forceinline__ void gl2lds16(const void* g, void* l) {
  __builtin_amdgcn_global_load_lds((const __attribute__((address_space(1))) void*)g,
                                   (__attribute__((address_space(3))) void*)l, 16, 0, 0);
}

// ---------------- elementwise fp32*scale -> bf16 hi (+ optional lo), vectorized x4
__global__ void split_f32_kernel(const float* __restrict__ in, u16t* __restrict__ hi,
                                 u16t* __restrict__ lo, int n4, float scale) {
  int i = blockIdx.x * blockDim.x + threadIdx.x;
  if (i >= n4) return;
  float4 v = ((const float4*)in)[i];
  float vv[4] = {v.x * scale, v.y * scale, v.z * scale, v.w * scale};
  ushort4v h, l;
  #pragma unroll
  for (int j = 0; j < 4; j++) {
    h[j] = f2bf(vv[j]);
    l[j] = f2bf(vv[j] - bf2f(h[j]));
  }
  ((ushort4v*)hi)[i] = h;
  if (lo) ((ushort4v*)lo)[i] = l;
}

// ---------------- transpose: in fp32 [K][Nc] -> bf16 [Nc][K]
__global__ void transpose_split_kernel(const float* __restrict__ in,
                                       u16t* __restrict__ hi, u16t* __restrict__ lo,
                                       int K, int Nc) {
  __shared__ float tile[32][33];
  const int n0 = blockIdx.x * 32, k0 = blockIdx.y * 32;
  const int tx = threadIdx.x, ty = threadIdx.y;
  #pragma unroll
  for (int j = 0; j < 32; j += 8)
    tile[ty + j][tx] = in[(size_t)(k0 + ty + j) * Nc + n0 + tx];
  __syncthreads();
  #pragma unroll
  for (int j = 0; j < 32; j += 8) {
    float v = tile[tx][ty + j];
    size_t o = (size_t)(n0 + ty + j) * K + k0 + tx;
    u16t h = f2bf(v);
    hi[o] = h;
    if (lo) lo[o] = f2bf(v - bf2f(h));
  }
}

// ---------------- GEMM 1: qkv = stream @ w_qkv + b_qkv
// A split hi/lo (2 MFMA streams), B hi only. Q pre-scaled by log2e for exp2 softmax.
__global__ __launch_bounds__(256, 3) void gemm_qkv_kernel(
    const u16t* __restrict__ Ahi, const u16t* __restrict__ Alo,
    const u16t* __restrict__ Bhi, const float* __restrict__ bias,
    u16t* __restrict__ Qhi, u16t* __restrict__ Qlo,
    u16t* __restrict__ Khi, u16t* __restrict__ Vt) {
  constexpr int BK = 64;
  __shared__ u16t sAh[128 * 64], sAl[128 * 64], sBh[128 * 64];
  const int t = threadIdx.x;
  const int lane = t & 63, wid = t >> 6;
  const int wm = wid >> 1, wn = wid & 1;
  const int g = lane >> 4, cc = lane & 15;
  const int m0 = blockIdx.x * 128, n0 = blockIdx.y * 128;
  const int srow = t >> 3;                           // 0..31 (+32 per iter)
  const int sc = ((t & 7) ^ ((t >> 3) & 7)) * 8;     // swizzled source chunk (u16)

  f32x4 acc[4][4] = {};

  for (int k0 = 0; k0 < DSTR; k0 += BK) {
    __syncthreads();
    #pragma unroll
    for (int i = 0; i < 4; i++) {
      const int row = i * 32 + srow;
      gl2lds16(Ahi + (size_t)(m0 + row) * DSTR + k0 + sc, &sAh[i * 2048 + wid * 512]);
      gl2lds16(Alo + (size_t)(m0 + row) * DSTR + k0 + sc, &sAl[i * 2048 + wid * 512]);
      gl2lds16(Bhi + (size_t)(n0 + row) * DSTR + k0 + sc, &sBh[i * 2048 + wid * 512]);
    }
    __syncthreads();
    #pragma unroll
    for (int kk = 0; kk < 2; kk++) {
      bf16x8 ah[4], al[4], bh[4];
      #pragma unroll
      for (int mt = 0; mt < 4; mt++) {
        const int r = wm * 64 + mt * 16 + cc;
        const int c = ((4 * kk + g) ^ (cc & 7)) * 8;
        ah[mt] = *(const bf16x8*)&sAh[r * 64 + c];
        al[mt] = *(const bf16x8*)&sAl[r * 64 + c];
      }
      #pragma unroll
      for (int nt = 0; nt < 4; nt++) {
        const int r = wn * 64 + nt * 16 + cc;
        const int c = ((4 * kk + g) ^ (cc & 7)) * 8;
        bh[nt] = *(const bf16x8*)&sBh[r * 64 + c];
      }
      #pragma unroll
      for (int mt = 0; mt < 4; mt++)
        #pragma unroll
        for (int nt = 0; nt < 4; nt++) {
          acc[mt][nt] = MFMA16(ah[mt], bh[nt], acc[mt][nt]);
          acc[mt][nt] = MFMA16(al[mt], bh[nt], acc[mt][nt]);
        }
    }
  }
  // epilogue: bias, scatter to Qhi/Qlo (log2e-scaled), Khi, plain Vt
  #pragma unroll
  for (int mt = 0; mt < 4; mt++)
    #pragma unroll
    for (int nt = 0; nt < 4; nt++)
      #pragma unroll
      for (int r = 0; r < 4; r++) {
        int grow = m0 + wm * 64 + mt * 16 + g * 4 + r;
        int gcol = n0 + wn * 64 + nt * 16 + cc;
        float val = acc[mt][nt][r] + bias[gcol];
        int nn = grow >> 1, bb = grow & 1;
        int hl = gcol / 192, off = gcol - hl * 192;
        int hh = bb * 16 + hl;
        if (off < 64) {
          val *= LOG2E;  // softmax runs in exp2 domain
          size_t o = ((size_t)hh * N_SEQ + nn) * 64 + off;
          u16t h_ = f2bf(val);
          Qhi[o] = h_;
          Qlo[o] = f2bf(val - bf2f(h_));
        } else if (off < 128) {
          Khi[((size_t)hh * N_SEQ + nn) * 64 + (off - 64)] = f2bf(val);
        } else {
          Vt[((size_t)hh * 64 + (off - 128)) * N_SEQ + nn] = f2bf(val);
        }
      }
}

// ---------------- flash attention: swapped QK^T (lane owns one q), 4 waves,
// QBLK=64, KVBLK=64, dbuf LDS K/V, exp2-domain softmax, defer-max,
// XOR-swizzled per-wave sP (chunk-aligned bijective store), scalar-u16 P stores.
__global__ __launch_bounds__(256, 4) void attn_kernel(
    const u16t* __restrict__ Qhi, const u16t* __restrict__ Qlo,
    const u16t* __restrict__ Khi, const u16t* __restrict__ Vt,
    const u16t* __restrict__ maskb, u16t* __restrict__ Vals) {
  __shared__ u16t sKh[2][64 * 64];
  __shared__ u16t sV[2][64 * 64];
  __shared__ u16t sP[4][16 * 64];
  const int t = threadIdx.x;
  const int lane = t & 63, wid = t >> 6;
  const int g = lane >> 4, cc = lane & 15;
  const int h = blockIdx.x >> 5;
  const int qt = blockIdx.x & 31;
  const int q0 = qt * 64 + wid * 16;

  const size_t kbase = (size_t)h * N_SEQ * 64;
  const size_t vbase = (size_t)h * 64 * N_SEQ;

  const int srow = t >> 3;                        // 0..31 (+32 second chunk)
  const int sc = ((t & 7) ^ ((t >> 3) & 7)) * 8;  // inverse-swizzled source chunk

  auto stage = [&](int buf, int mt0) {
    gl2lds16(Khi + kbase + (size_t)(mt0 + srow) * 64 + sc,      &sKh[buf][wid * 512]);
    gl2lds16(Khi + kbase + (size_t)(mt0 + srow + 32) * 64 + sc, &sKh[buf][2048 + wid * 512]);
    gl2lds16(Vt + vbase + (size_t)srow * N_SEQ + mt0 + sc,        &sV[buf][wid * 512]);
    gl2lds16(Vt + vbase + (size_t)(srow + 32) * N_SEQ + mt0 + sc, &sV[buf][2048 + wid * 512]);
  };

  const size_t qoff = kbase + (size_t)(q0 + cc) * 64 + g * 8;
  bf16x8 qh0 = *(const bf16x8*)(Qhi + qoff);
  bf16x8 qh1 = *(const bf16x8*)(Qhi + qoff + 32);
  bf16x8 ql0 = *(const bf16x8*)(Qlo + qoff);
  bf16x8 ql1 = *(const bf16x8*)(Qlo + qoff + 32);

  f32x4 o[4] = {};
  float M = -1e30f, L = 0.0f;   // per-lane: q = q0 + cc (log2 domain)

  stage(0, 0);
  int cur = 0;
  const int sw = (cc & 7) * 8;
  u16t* sPw = sP[wid];
  const int alane = (lane & 48) + g * 4;  // base src lane for row-state gathers

  for (int ti = 0; ti < N_SEQ / 64; ++ti) {
    const int mt0 = ti * 64;
    __syncthreads();  // staging of buf[cur] complete; all waves off buf[cur^1]
    if (ti + 1 < N_SEQ / 64) stage(cur ^ 1, mt0 + 64);

    // mask in natural [q][k] layout: 4 x b64, rows = this lane's q
    ushort4v ml[4];
    #pragma unroll
    for (int mt = 0; mt < 4; ++mt)
      ml[mt] = *(const ushort4v*)&maskb[(size_t)(q0 + cc) * N_SEQ + mt0 + mt * 16 + g * 4];

    // swapped QK^T: D[key][q] -> lane holds 16 key-scores for q = q0+cc
    f32x4 s[4];
    #pragma unroll
    for (int mt = 0; mt < 4; ++mt) {
      const int krow = (mt * 16 + cc) * 64;
      bf16x8 kh0 = *(const bf16x8*)&sKh[cur][krow + ((g * 8) ^ sw)];
      bf16x8 kh1 = *(const bf16x8*)&sKh[cur][krow + ((32 + g * 8) ^ sw)];
      f32x4 a = {};
      a = MFMA16(kh0, qh0, a);
      a = MFMA16(kh1, qh1, a);
      a = MFMA16(kh0, ql0, a);
      a = MFMA16(kh1, ql1, a);
      s[mt] = a;
    }
    // mask add + in-lane max (16 values), then 2 cross-g shuffles
    float pm = -1e30f;
    #pragma unroll
    for (int mt = 0; mt < 4; ++mt)
      #pragma unroll
      for (int r = 0; r < 4; ++r) {
        s[mt][r] += bf2f(ml[mt][r]);
        pm = fmaxf(pm, s[mt][r]);
      }
    pm = fmaxf(pm, __shfl_xor(pm, 16));
    pm = fmaxf(pm, __shfl_xor(pm, 32));

    if (__any(pm - M > 11.54f)) {  // defer-max (log2 units)
      float nM = fmaxf(M, pm);
      float alpha = exp2a(M - nM);
      L *= alpha;
      M = nM;
      float ar[4];
      #pragma unroll
      for (int r = 0; r < 4; ++r) ar[r] = __shfl(alpha, alane + r);
      #pragma unroll
      for (int dt = 0; dt < 4; ++dt)
        #pragma unroll
        for (int r = 0; r < 4; ++r) o[dt][r] *= ar[r];
    }

    float p[4][4];
    float rs = 0.0f;
    #pragma unroll
    for (int mt = 0; mt < 4; ++mt)
      #pragma unroll
      for (int r = 0; r < 4; ++r) {
        p[mt][r] = exp2a(s[mt][r] - M);
        rs += p[mt][r];
      }
    rs += __shfl_xor(rs, 16);
    rs += __shfl_xor(rs, 32);
    L += rs;

    // P store: element k = mt*16 + g*4 + r must land at ((k&~7)^sw) + (k&7).
    // kb = aligned 8-chunk base; (g&1)*4 = in-chunk offset. Bijective, matches
    // the b128 read below (previous round XOR'd before adding the offset ->
    // bit-3 carry for odd cc, g>=2 scribbled the neighbor chunk).
    #pragma unroll
    for (int mt = 0; mt < 4; ++mt) {
      unsigned w0 = cvt_pk_bf16(p[mt][0], p[mt][1]);
      unsigned w1 = cvt_pk_bf16(p[mt][2], p[mt][3]);
      const int kb = mt * 16 + (g >> 1) * 8;
      u16t* P = &sPw[cc * 64 + (kb ^ sw) + (g & 1) * 4];
      P[0] = (u16t)w0; P[1] = (u16t)(w0 >> 16);
      P[2] = (u16t)w1; P[3] = (u16t)(w1 >> 16);
    }
    bf16x8 pf0 = *(const bf16x8*)&sPw[cc * 64 + ((g * 8) ^ sw)];
    bf16x8 pf1 = *(const bf16x8*)&sPw[cc * 64 + ((32 + g * 8) ^ sw)];
    #pragma unroll
    for (int dt = 0; dt < 4; ++dt) {
      const int vrow = (dt * 16 + cc) * 64;
      bf16x8 v0 = *(const bf16x8*)&sV[cur][vrow + ((g * 8) ^ sw)];
      bf16x8 v1 = *(const bf16x8*)&sV[cur][vrow + ((32 + g * 8) ^ sw)];
      o[dt] = MFMA16(pf0, v0, o[dt]);
      o[dt] = MFMA16(pf1, v1, o[dt]);
    }
    cur ^= 1;
  }
  float invL = 1.0f / L;
  float ir[4];
  #pragma unroll
  for (int r = 0; r < 4; ++r) ir[r] = __shfl(invL, alane + r);
  const int bb = h >> 4, hl = h & 15;
  #pragma unroll
  for (int r = 0; r < 4; ++r) {
    const int q = q0 + g * 4 + r;
    const size_t orow = (size_t)(q * 2 + bb) * DSTR + hl * 64;
    #pragma unroll
    for (int dt = 0; dt < 4; ++dt)
      Vals[orow + dt * 16 + cc] = f2bf(o[dt][r] * ir[r]);
  }
}

// ---------------- GEMM 3: out = Vals @ w_out + b_out (plain bf16, m97-style)
__global__ __launch_bounds__(256, 3) void gemm_out_kernel(
    const u16t* __restrict__ A, const u16t* __restrict__ Bt,
    const float* __restrict__ bias, float* __restrict__ out) {
  constexpr int BK = 64;
  __shared__ u16t sA[128 * 64], sB[128 * 64];
  const int t = threadIdx.x;
  const int lane = t & 63, wid = t >> 6;
  const int wm = wid >> 1, wn = wid & 1;
  const int g = lane >> 4, cc = lane & 15;
  const int m0 = blockIdx.x * 128, n0 = blockIdx.y * 128;
  const int srow = t >> 3;
  const int sc = ((t & 7) ^ ((t >> 3) & 7)) * 8;

  f32x4 acc[4][4] = {};
  for (int k0 = 0; k0 < DSTR; k0 += BK) {
    __syncthreads();
    #pragma unroll
    for (int i = 0; i < 4; i++) {
      const int row = i * 32 + srow;
      gl2lds16(A + (size_t)(m0 + row) * DSTR + k0 + sc, &sA[i * 2048 + wid * 512]);
      gl2lds16(Bt + (size_t)(n0 + row) * DSTR + k0 + sc, &sB[i * 2048 + wid * 512]);
    }
    __syncthreads();
    #pragma unroll
    for (int kk = 0; kk < 2; kk++) {
      bf16x8 af[4], bfr[4];
      #pragma unroll
      for (int mt = 0; mt < 4; mt++) {
        const int r = wm * 64 + mt * 16 + cc;
        const int c = ((4 * kk + g) ^ (cc & 7)) * 8;
        af[mt] = *(const bf16x8*)&sA[r * 64 + c];
      }
      #pragma unroll
      for (int nt = 0; nt < 4; nt++) {
        const int r = wn * 64 + nt * 16 + cc;
        const int c = ((4 * kk + g) ^ (cc & 7)) * 8;
        bfr[nt] = *(const bf16x8*)&sB[r * 64 + c];
      }
      #pragma unroll
      for (int mt = 0; mt < 4; mt++)
        #pragma unroll
        for (int nt = 0; nt < 4; nt++)
          acc[mt][nt] = MFMA16(af[mt], bfr[nt], acc[mt][nt]);
    }
  }
  #pragma unroll
  for (int mt = 0; mt < 4; mt++)
    #pragma unroll
    for (int nt = 0; nt < 4; nt++)
      #pragma unroll
      for (int r = 0; r < 4; r++) {
        int grow = m0 + wm * 64 + mt * 16 + g * 4 + r;
        int gcol = n0 + wn * 64 + nt * 16 + cc;
        out[(size_t)grow * DSTR + gcol] = acc[mt][nt][r] + bias[gcol];
      }
}

extern "C" void kernel_launch(void* const* d_in, const int* in_sizes, int n_in,
                              void* d_out, int out_size, void* d_ws, size_t ws_size,
                              hipStream_t stream) {
  (void)in_sizes; (void)n_in; (void)out_size; (void)ws_size;
  const float* x      = (const float*)d_in[0];
  const float* mask   = (const float*)d_in[1];
  const float* w_qkv  = (const float*)d_in[2];
  const float* b_qkv  = (const float*)d_in[3];
  const float* w_out  = (const float*)d_in[4];
  const float* b_out  = (const float*)d_in[5];
  float* out = (float*)d_out;

  char* ws = (char*)d_ws;
  size_t off = 0;
  auto alloc = [&](size_t n) { void* p = ws + off; off += (n + 255) & ~(size_t)255; return p; };
  u16t* WqkvT = (u16t*)alloc((size_t)QKVN * DSTR * 2);
  u16t* WoutT = (u16t*)alloc((size_t)DSTR * DSTR * 2);
  u16t* Qhi = (u16t*)alloc((size_t)NH * N_SEQ * 64 * 2);
  u16t* Qlo = (u16t*)alloc((size_t)NH * N_SEQ * 64 * 2);
  u16t* Khi = (u16t*)alloc((size_t)NH * N_SEQ * 64 * 2);
  u16t* Vt  = (u16t*)alloc((size_t)NH * 64 * N_SEQ * 2);
  u16t* Xhi = (u16t*)alloc((size_t)MROWS * DSTR * 2);  // reused as Vals after gemm_qkv
  u16t* Xlo = (u16t*)alloc((size_t)MROWS * DSTR * 2);
  u16t* MaskB = (u16t*)alloc((size_t)N_SEQ * N_SEQ * 2);
  u16t* Vals = Xhi;  // alias: X consumed by gemm_qkv before attn writes Vals

  split_f32_kernel<<<dim3(MROWS * DSTR / 4 / 256), 256, 0, stream>>>(
      x, Xhi, Xlo, MROWS * DSTR / 4, 1.0f);
  split_f32_kernel<<<dim3(N_SEQ * N_SEQ / 4 / 256), 256, 0, stream>>>(
      mask, MaskB, nullptr, N_SEQ * N_SEQ / 4, LOG2E);
  transpose_split_kernel<<<dim3(QKVN / 32, DSTR / 32), dim3(32, 8), 0, stream>>>(
      w_qkv, WqkvT, nullptr, DSTR, QKVN);
  transpose_split_kernel<<<dim3(DSTR / 32, DSTR / 32), dim3(32, 8), 0, stream>>>(
      w_out, WoutT, nullptr, DSTR, DSTR);
  gemm_qkv_kernel<<<dim3(MROWS / 128, QKVN / 128), 256, 0, stream>>>(
      Xhi, Xlo, WqkvT, b_qkv, Qhi, Qlo, Khi, Vt);
  attn_kernel<<<dim3(NH * (N_SEQ / 64)), 256, 0, stream>>>(
      Qhi, Qlo, Khi, Vt, MaskB, Vals);
  gemm_out_kernel<<<dim3(MROWS / 128, DSTR / 128), 256, 0, stream>>>(
      Vals, WoutT, b_out, out);
}